// Round 1
// baseline (432.909 us; speedup 1.0000x reference)
//
#include <hip/hip_runtime.h>

#define D 64
#define TILE 64
#define SAB 72    // bf16 LDS row stride (elements); 2-way bank alias = free
#define CAP 48    // per-node neighbor capacity; Poisson(16) => P(deg>=48) ~ 1e-9
#define CSTR 65   // lds_col row stride (ints): 65 == 1 mod 32 -> conflict-free

#define NB 256    // dst buckets of 512 nodes: b = dst >> 9
#define BCAP 32   // per-bucket LDS staging slots (mean 16/chunk)
#define CHUNK 4096
#define GCAP 9216 // per-bucket capacity (mean 8163, sd ~90 => 11 sd margin)

typedef short short8 __attribute__((ext_vector_type(8)));
typedef float floatx4 __attribute__((ext_vector_type(4)));

// ---------------- helpers ----------------

__device__ __forceinline__ unsigned int bf16rn(float f) {
    unsigned int u = __float_as_uint(f);
    return (u + 0x7FFFu + ((u >> 16) & 1u)) >> 16;  // round-to-nearest-even
}

__device__ __forceinline__ void addu(float a[8], const uint4 v) {
    a[0] += __uint_as_float(v.x << 16);
    a[1] += __uint_as_float(v.x & 0xFFFF0000u);
    a[2] += __uint_as_float(v.y << 16);
    a[3] += __uint_as_float(v.y & 0xFFFF0000u);
    a[4] += __uint_as_float(v.z << 16);
    a[5] += __uint_as_float(v.z & 0xFFFF0000u);
    a[6] += __uint_as_float(v.w << 16);
    a[7] += __uint_as_float(v.w & 0xFFFF0000u);
}

// ---------------- fused prep: edge binning + bf16 converts in ONE dispatch ----------------
// Blocks [0, nchunks): bin 4096 edges each into 256 dst-buckets via LDS staging.
// Blocks [nchunks, nchunks+cvtb): convert x to bf16 in CHUNK-MAJOR (feature-sliced)
//   layout xb[c][node][8] via LDS transpose (coalesced in AND out).
// Blocks [nchunks+cvtb, +28): convert weights (transposed to B-frag layout).

__global__ __launch_bounds__(1024) void prep_kernel(
    const int* __restrict__ src, const int* __restrict__ dst, int E, int nchunks, int cvtb,
    int* __restrict__ bcnt, unsigned int* __restrict__ bpairs,
    const float* __restrict__ x, unsigned short* __restrict__ xb, int N,
    const float* __restrict__ w0, const float* __restrict__ w1,
    const float* __restrict__ w2, const float* __restrict__ w3,
    const float* __restrict__ w4, const float* __restrict__ w5,
    const float* __restrict__ w6, unsigned short* __restrict__ wtb) {
    __shared__ unsigned int smem[NB * BCAP + NB];  // 33.8 KB; aliased by both paths
    const int t = threadIdx.x;

    if (blockIdx.x >= nchunks) {
        const int cb = blockIdx.x - nchunks;
        if (cb < cvtb) {
            // ---- x convert path: 256 nodes/block, 2 rounds of 128 via LDS transpose ----
            unsigned int* ldst = smem;  // [128][33] u32
            const int nodebase = cb * 256;
            for (int rr = 0; rr < 2; ++rr) {
                const int nb = nodebase + rr * 128;
                if (rr) __syncthreads();  // protect LDS reuse across rounds
                const int nloc = t >> 3, sub = t & 7;
                const int node = nb + nloc;
                if (node < N) {
                    const float4* p = (const float4*)(x + (size_t)node * D + sub * 8);
                    const float4 v0 = p[0], v1 = p[1];
                    unsigned int* d = &ldst[nloc * 33 + sub * 4];
                    d[0] = bf16rn(v0.x) | (bf16rn(v0.y) << 16);
                    d[1] = bf16rn(v0.z) | (bf16rn(v0.w) << 16);
                    d[2] = bf16rn(v1.x) | (bf16rn(v1.y) << 16);
                    d[3] = bf16rn(v1.z) | (bf16rn(v1.w) << 16);
                }
                __syncthreads();
                const int cc = t >> 7, n2 = t & 127;
                const int node2 = nb + n2;
                if (node2 < N) {
                    const unsigned int* s = &ldst[n2 * 33 + cc * 4];
                    uint4 o;
                    o.x = s[0]; o.y = s[1]; o.z = s[2]; o.w = s[3];
                    *(uint4*)(xb + ((size_t)cc * N + node2) * 8) = o;  // contiguous per chunk
                }
            }
            return;
        }
        // ---- weight convert path ----
        const int idx = (cb - cvtb) * 1024 + t;
        if (idx < 7 * 4096) {
            const float* ws[7] = {w0, w1, w2, w3, w4, w5, w6};
            const int mtx = idx >> 12;
            const int within = idx & 4095;
            const int c = within >> 6, k = within & 63;
            wtb[idx] = (unsigned short)bf16rn(ws[mtx][k * 64 + c]);
        }
        return;
    }

    // ---- bin path (unchanged) ----
    unsigned int* lbuf = smem;                 // [NB][BCAP]
    int* lcnt = (int*)(smem + NB * BCAP);      // [NB]
    if (t < NB) lcnt[t] = 0;
    __syncthreads();
    const int base = blockIdx.x * CHUNK;
    const int end = (base + CHUNK < E) ? base + CHUNK : E;
    for (int i = base + t; i < end; i += 1024) {
        const int d = dst[i];
        const int b = d >> 9;
        const unsigned int u = ((unsigned int)src[i] << 9) | (unsigned int)(d & 511);
        const int slot = atomicAdd(&lcnt[b], 1);
        if (slot < BCAP) {
            lbuf[b * BCAP + slot] = u;
        } else {  // rare overflow: direct global path
            const int p = atomicAdd(&bcnt[b], 1);
            if (p < GCAP) bpairs[(size_t)b * GCAP + p] = u;
        }
    }
    __syncthreads();
    if (t < NB) {
        const int b = t;
        int n0 = lcnt[b];
        if (n0 > BCAP) n0 = BCAP;
        if (n0 > 0) {
            const int p = atomicAdd(&bcnt[b], n0);
            for (int j = 0; j < n0 && p + j < GCAP; j++)
                bpairs[(size_t)b * GCAP + p + j] = lbuf[b * BCAP + j];
        }
    }
}

// One block per 512-node bucket (unchanged).
__global__ __launch_bounds__(1024) void debucket_kernel(const int* __restrict__ bcnt,
                                                        const unsigned int* __restrict__ bpairs,
                                                        int* __restrict__ cnt,
                                                        int* __restrict__ colA, int n) {
    __shared__ int lcnt[512];
    const int b = blockIdx.x;
    if (threadIdx.x < 512) lcnt[threadIdx.x] = 0;
    __syncthreads();
    int n0 = bcnt[b];
    if (n0 > GCAP) n0 = GCAP;
    for (int i = threadIdx.x; i < n0; i += 1024) {
        const unsigned int u = bpairs[(size_t)b * GCAP + i];
        const int dl = (int)(u & 511u);
        const int s = (int)(u >> 9);
        const int p = atomicAdd(&lcnt[dl], 1);
        if (p < CAP) colA[(size_t)((b << 9) | dl) * CAP + p] = s;
    }
    __syncthreads();
    if (threadIdx.x < 512) {
        const int d = (b << 9) | threadIdx.x;
        if (d < n) cnt[d] = lcnt[threadIdx.x];
    }
}

// ---------------- MFMA MLP helpers (unchanged math) ----------------
// 16x16x32 bf16. A: m=lane&15, k=(lane>>4)*8+j. B: n=lane&15 (from wt[n*64+k]).
// C/D: col=lane&15, row=(lane>>4)*4+reg.

__device__ __forceinline__ void mfma_mm(const unsigned short* Abase,
                                        const unsigned short* __restrict__ wt,
                                        int m, int q, floatx4 c[4]) {
    const short8 a0 = *(const short8*)(Abase);
    const short8 a1 = *(const short8*)(Abase + 32);
#pragma unroll
    for (int tt = 0; tt < 4; tt++) {
        const short8 b0 = *(const short8*)&wt[(tt * 16 + m) * 64 + q * 8];
        const short8 b1 = *(const short8*)&wt[(tt * 16 + m) * 64 + 32 + q * 8];
        c[tt] = __builtin_amdgcn_mfma_f32_16x16x32_bf16(a0, b0, c[tt], 0, 0, 0);
        c[tt] = __builtin_amdgcn_mfma_f32_16x16x32_bf16(a1, b1, c[tt], 0, 0, 0);
    }
}

__device__ __forceinline__ void relu_pack(floatx4 c[4], const float* __restrict__ bias,
                                          unsigned short* Awr, int m, int q) {
#pragma unroll
    for (int tt = 0; tt < 4; tt++) {
        const float bv = bias[tt * 16 + m];
#pragma unroll
        for (int i = 0; i < 4; i++) {
            const float v = fmaxf(c[tt][i] + bv, 0.f);
            Awr[(q * 4 + i) * SAB + tt * 16 + m] = (unsigned short)bf16rn(v);
        }
    }
}

// ---------------- fused GIN block (+optional final linear) ----------------
// NEW structure: activations live in chunk-major slabs xb[c][N][8] (1.6 MB each).
// 128 threads: lane = row (64 rows/tile), half = t>>6 owns 4 of the 8 chunks.
// Col lists staged once into LDS (transposed [k][row]); gather sweeps chunks in
// XCD-staggered order ((bid&7)+phase) so each XCD's L2 holds ~2 slabs -> hits.

__global__ __launch_bounds__(128) void gin_kernel(
    const unsigned short* __restrict__ xb,  // bf16 activations, chunk-major [8][N][8]
    const int* __restrict__ cnt, const int* __restrict__ colA,
    const unsigned short* __restrict__ w1t, const float* __restrict__ bias1,
    const unsigned short* __restrict__ w2t, const float* __restrict__ bias2,
    const unsigned short* __restrict__ wft, const float* __restrict__ biasf,  // nullable
    unsigned short* __restrict__ outb,  // bf16 out, chunk-major (blocks 0,1)
    float* __restrict__ outf,           // fp32 out row-major (final block)
    int n) {
    __shared__ int lds_col[CAP * CSTR];        // 12,480 B, transposed [k][row]
    __shared__ unsigned short Ab[TILE * SAB];  // 9,216 B
    const int t = threadIdx.x;
    const int lane = t & 63;
    const int half = t >> 6;
    const int base = blockIdx.x * TILE;
    const size_t N8 = (size_t)n * 8;

    // ---- stage col lists: 12 KB contiguous global -> LDS transposed ----
    {
        const int4* cs = (const int4*)(colA + (size_t)base * CAP);
#pragma unroll
        for (int i = 0; i < 6; ++i) {
            const int j = t + i * 128;           // 768 int4 = 64 rows * 48 cols
            const int4 v = cs[j];
            const int r = j / 12;
            const int k0 = (j % 12) * 4;
            lds_col[(k0 + 0) * CSTR + r] = v.x;
            lds_col[(k0 + 1) * CSTR + r] = v.y;
            lds_col[(k0 + 2) * CSTR + r] = v.z;
            lds_col[(k0 + 3) * CSTR + r] = v.w;
        }
    }
    const int row = lane;
    const int nn = base + row;
    int c = 0;
    if (nn < n) { c = cnt[nn]; if (c > CAP) c = CAP; }
    __syncthreads();

    // ---- gather: 4 chunk-phases per half-wave, XCD-staggered slab sweep ----
    const int xcd = blockIdx.x & 7;
#pragma unroll
    for (int ph = 0; ph < 4; ++ph) {
        const int chunk = (xcd + half * 4 + ph) & 7;
        const unsigned short* xs = xb + (size_t)chunk * N8;
        float a[8] = {0.f, 0.f, 0.f, 0.f, 0.f, 0.f, 0.f, 0.f};
        if (nn < n) addu(a, *(const uint4*)(xs + (size_t)nn * 8));  // self term
        int k = 0;
        for (; k + 4 <= c; k += 4) {
            const int s0 = lds_col[(k + 0) * CSTR + row];
            const int s1 = lds_col[(k + 1) * CSTR + row];
            const int s2 = lds_col[(k + 2) * CSTR + row];
            const int s3 = lds_col[(k + 3) * CSTR + row];
            const uint4 v0 = *(const uint4*)(xs + (size_t)s0 * 8);
            const uint4 v1 = *(const uint4*)(xs + (size_t)s1 * 8);
            const uint4 v2 = *(const uint4*)(xs + (size_t)s2 * 8);
            const uint4 v3 = *(const uint4*)(xs + (size_t)s3 * 8);
            addu(a, v0); addu(a, v1); addu(a, v2); addu(a, v3);
        }
        for (; k < c; k++) {
            const int s0 = lds_col[k * CSTR + row];
            addu(a, *(const uint4*)(xs + (size_t)s0 * 8));
        }
        uint4 o;
        o.x = bf16rn(a[0]) | (bf16rn(a[1]) << 16);
        o.y = bf16rn(a[2]) | (bf16rn(a[3]) << 16);
        o.z = bf16rn(a[4]) | (bf16rn(a[5]) << 16);
        o.w = bf16rn(a[6]) | (bf16rn(a[7]) << 16);
        *(uint4*)&Ab[row * SAB + chunk * 8] = o;
    }
    __syncthreads();

    // ---- MLP: each half-wave owns 2 sets of 16 rows (rows half*32 .. +31) ----
    const int m = lane & 15;
    const int q = lane >> 4;
#pragma unroll
    for (int s = 0; s < 2; ++s) {
        const int row0 = (half * 2 + s) * 16;
        const unsigned short* Abase = &Ab[(row0 + m) * SAB + q * 8];
        unsigned short* Awr = &Ab[row0 * SAB];

        // mm1: relu(A @ W1 + b1) -> A
        {
            floatx4 cc[4] = {{0.f, 0.f, 0.f, 0.f}, {0.f, 0.f, 0.f, 0.f},
                             {0.f, 0.f, 0.f, 0.f}, {0.f, 0.f, 0.f, 0.f}};
            mfma_mm(Abase, w1t, m, q, cc);
            relu_pack(cc, bias1, Awr, m, q);
        }
        // mm2: A @ W2 + b2
        {
            floatx4 cc[4] = {{0.f, 0.f, 0.f, 0.f}, {0.f, 0.f, 0.f, 0.f},
                             {0.f, 0.f, 0.f, 0.f}, {0.f, 0.f, 0.f, 0.f}};
            mfma_mm(Abase, w2t, m, q, cc);
            relu_pack(cc, bias2, Awr, m, q);  // relu(out) packed back to Ab
        }

        if (wft) {
            // final head: A @ Wf + bf -> fp32 row-major out (no relu)
            floatx4 cc[4] = {{0.f, 0.f, 0.f, 0.f}, {0.f, 0.f, 0.f, 0.f},
                             {0.f, 0.f, 0.f, 0.f}, {0.f, 0.f, 0.f, 0.f}};
            mfma_mm(Abase, wft, m, q, cc);
#pragma unroll
            for (int tt = 0; tt < 4; tt++) {
                const float bv = biasf[tt * 16 + m];
#pragma unroll
                for (int i = 0; i < 4; i++) {
                    const int no = base + row0 + q * 4 + i;
                    if (no < n) outf[(size_t)no * D + tt * 16 + m] = cc[tt][i] + bv;
                }
            }
        } else {
            // bulk transposed store: 16B coalesced per chunk from the packed LDS tile
#pragma unroll
            for (int pass = 0; pass < 2; ++pass) {
                const int cch = q + pass * 4;
                const int r = row0 + m;
                const int no = base + r;
                if (no < n)
                    *(uint4*)(outb + ((size_t)cch * (size_t)n + no) * 8) =
                        *(const uint4*)&Ab[r * SAB + cch * 8];
            }
        }
    }
}

// ---------------- launch ----------------

extern "C" void kernel_launch(void* const* d_in, const int* in_sizes, int n_in,
                              void* d_out, int out_size, void* d_ws, size_t ws_size,
                              hipStream_t stream) {
    const float* x = (const float*)d_in[0];
    const int* eidx = (const int*)d_in[1];
    const int N = in_sizes[0] / D;
    const int E = in_sizes[1] / 2;

    const float* w1b[3] = {(const float*)d_in[2], (const float*)d_in[6], (const float*)d_in[10]};
    const float* b1b[3] = {(const float*)d_in[3], (const float*)d_in[7], (const float*)d_in[11]};
    const float* w2b[3] = {(const float*)d_in[4], (const float*)d_in[8], (const float*)d_in[12]};
    const float* b2b[3] = {(const float*)d_in[5], (const float*)d_in[9], (const float*)d_in[13]};
    const float* wf = (const float*)d_in[14];
    const float* bf = (const float*)d_in[15];
    float* out = (float*)d_out;

    // workspace: cnt[N] | bcnt[NB] | colA[N*CAP] | xbA | xbB | wtb[7*4096 bf16]
    // bpairs (9.4 MB) aliases xbB (dead once debucket completes, before gin0 writes).
    int* cnt = (int*)d_ws;
    int* bcnt = cnt + N;
    int* colA = bcnt + NB;
    unsigned short* xbA = (unsigned short*)(colA + (size_t)N * CAP);
    unsigned short* xbB = xbA + (size_t)N * D;
    unsigned int* bpairs = (unsigned int*)xbB;
    unsigned short* wtb = xbB + (size_t)N * D;

    const int* srcP = eidx;
    const int* dstP = eidx + E;

    (void)hipMemsetAsync(bcnt, 0, (size_t)NB * 4, stream);
    const int nchunks = (E + CHUNK - 1) / CHUNK;
    const int cvtb = (N + 255) >> 8;          // 256 nodes per convert block
    const int wb = (7 * 4096 + 1023) / 1024;  // 28 weight-convert blocks
    // wtb order: [w1_0, w2_0, w1_1, w2_1, w1_2, w2_2, wf]
    prep_kernel<<<nchunks + cvtb + wb, 1024, 0, stream>>>(
        srcP, dstP, E, nchunks, cvtb, bcnt, bpairs,
        x, xbA, N, w1b[0], w2b[0], w1b[1], w2b[1], w1b[2], w2b[2], wf, wtb);
    debucket_kernel<<<(N + 511) >> 9, 1024, 0, stream>>>(bcnt, bpairs, cnt, colA, N);

    const int grid = (N + TILE - 1) / TILE;
    gin_kernel<<<grid, 128, 0, stream>>>(xbA, cnt, colA,
                                         wtb + 0 * 4096, b1b[0], wtb + 1 * 4096, b2b[0],
                                         nullptr, nullptr, xbB, nullptr, N);
    gin_kernel<<<grid, 128, 0, stream>>>(xbB, cnt, colA,
                                         wtb + 2 * 4096, b1b[1], wtb + 3 * 4096, b2b[1],
                                         nullptr, nullptr, xbA, nullptr, N);
    gin_kernel<<<grid, 128, 0, stream>>>(xbA, cnt, colA,
                                         wtb + 4 * 4096, b1b[2], wtb + 5 * 4096, b2b[2],
                                         wtb + 6 * 4096, bf, nullptr, out, N);
}